// Round 8
// baseline (4555.889 us; speedup 1.0000x reference)
//
#include <hip/hip_runtime.h>
#include <hip/hip_bf16.h>
#include <stdint.h>

// Problem constants
#define B_    128
#define T_    1024
#define IN_   256
#define L_    1024
#define OUT_  256
#define KTOT  1280   // IN_ + L_

// Wave-agent decomposition: 8 groups x 64 wave-agents; each wave owns
// 16 batches x 16 latent cols with FULL K=1280 (no cross-wave reduction,
// no __syncthreads in the loop). 256 WGs x 128 threads (2 waves/WG).
#define GROUPS  8
#define NB      16
#define NCW     16          // cols per wave-agent
#define NWAVE   64          // wave-agents per group
#define WROW_B   2560u      // bytes per weight row (1280 bf16)
#define WSLICE_B 40960u     // bytes per wave slice (16 rows)
#define LDS_TOTAL (2 * WSLICE_B)   // 81920

using short8 = __attribute__((ext_vector_type(8))) short;
using bf16x8 = __attribute__((ext_vector_type(8))) __bf16;
using f32x4  = __attribute__((ext_vector_type(4))) float;

__device__ __forceinline__ unsigned short f2b(float f) {   // fp32 -> bf16 RNE
  unsigned u = __builtin_bit_cast(unsigned, f);
  u += 0x7FFFu + ((u >> 16) & 1u);
  return (unsigned short)(u >> 16);
}
__device__ __forceinline__ float b2f(unsigned short h) {
  unsigned u = ((unsigned)h) << 16;
  return __builtin_bit_cast(float, u);
}
__device__ __forceinline__ float fast_tanh(float z) {
  z = fminf(fmaxf(z, -30.f), 30.f);
  float e2 = __expf(2.f * z);
  return __fdividef(e2 - 1.f, e2 + 1.f);
}
__device__ __forceinline__ short8 cvt8(f32x4 a, f32x4 b) {
  short8 v;
  v[0] = (short)f2b(a[0]); v[1] = (short)f2b(a[1]);
  v[2] = (short)f2b(a[2]); v[3] = (short)f2b(a[3]);
  v[4] = (short)f2b(b[0]); v[5] = (short)f2b(b[1]);
  v[6] = (short)f2b(b[2]); v[7] = (short)f2b(b[3]);
  return v;
}
// Device-scope (sc1) data movement — coherent across XCDs at the MALL.
__device__ __forceinline__ void st_us(unsigned short* p, unsigned short v) {
  asm volatile("global_store_short %0, %1, off sc1" :: "v"(p), "v"(v) : "memory");
}
__device__ __forceinline__ void ld_x4(short8& d, const unsigned short* p) {
  asm volatile("global_load_dwordx4 %0, %1, off sc1 nt" : "=v"(d) : "v"(p) : "memory");
}

__global__ __launch_bounds__(128, 1)
void rnn_persistent(const float* __restrict__ x, const float* __restrict__ Wlin,
                    unsigned short* __restrict__ h0buf, unsigned short* __restrict__ h1buf,
                    unsigned int* __restrict__ flags)
{
  extern __shared__ char smem[];     // [2 waves][16 rows][1280] bf16, XOR-swizzled
  const int tid = threadIdx.x;
  const int g   = blockIdx.x & 7;    // batch group (XCD heuristic only)
  const int ww  = blockIdx.x >> 3;   // 0..31: 32-col slab
  const int bb  = g * NB;

  // ---- one-time: stage W rows [ww*32, ww*32+32) into swizzled LDS ----
  // Swizzle: byte ^= (row&7)<<4  (spreads the 2560B row stride across banks;
  // residual 2-way conflicts are free per m136).
  for (int rr = 0; rr < 32; ++rr) {
    const float* wrow = Wlin + (size_t)(ww * 32 + rr) * KTOT;
    const unsigned sbase = (unsigned)(rr >> 4) * WSLICE_B + (unsigned)(rr & 15) * WROW_B;
    const unsigned swr   = ((unsigned)(rr & 7)) << 4;
    for (int k = tid; k < KTOT; k += 128)
      *(short*)(smem + ((sbase + (unsigned)k * 2u) ^ swr)) = (short)f2b(wrow[k]);
  }
  __syncthreads();                   // the ONLY barrier; loop below is barrier-free

  const int wv  = tid >> 6;          // wave 0..1 within WG
  const int l   = tid & 63;
  const int r   = l & 15;            // A-row (batch) / output col within tile
  const int lk8 = (l >> 4) * 8;      // K sub-offset
  const int wid = ww * 2 + wv;       // wave-agent id in group, 0..63
  const int cc  = ww * 32 + wv * 16; // first output col
  const char* wbase  = smem + wv * WSLICE_B + (unsigned)r * WROW_B;
  const unsigned swz = ((unsigned)(r & 7)) << 4;

  unsigned int* myflag = flags + (size_t)(g * NWAVE + wid) * 16;   // 64B apart
  const unsigned int* pollp = flags + (size_t)(g * NWAVE + l) * 16; // lane l : agent l

  for (int t = 0; t < T_; ++t) {
    const unsigned short* hcur = (t & 1) ? h1buf : h0buf;
    unsigned short*       hnxt = (t & 1) ? h0buf : h1buf;

    f32x4 acc[4] = {{0,0,0,0},{0,0,0,0},{0,0,0,0},{0,0,0,0}};  // 4 indep chains

    // ---- x part (K 0..255): before the poll, hides peer-finish latency ----
    const float* xrow = x + ((size_t)(bb + r) * T_ + t) * IN_;
    #pragma unroll
    for (int ks = 0; ks < 8; ++ks) {
      const int k = ks * 32 + lk8;
      short8 a = cvt8(*(const f32x4*)(xrow + k), *(const f32x4*)(xrow + k + 4));
      short8 b = *(const short8*)(wbase + (((unsigned)k * 2u) ^ swz));
      acc[ks & 3] = __builtin_amdgcn_mfma_f32_16x16x32_bf16(
                      __builtin_bit_cast(bf16x8, a), __builtin_bit_cast(bf16x8, b),
                      acc[ks & 3], 0, 0, 0);
    }

    // ---- h part (t=0: h is zero, skip) ----
    if (t > 0) {
      // 64 lanes poll 64 agent flags in one load; exit when all peers published h_t.
      while (true) {
        unsigned v = __hip_atomic_load(pollp, __ATOMIC_RELAXED, __HIP_MEMORY_SCOPE_AGENT);
        if (__all((int)(v >= (unsigned)t))) break;
        __builtin_amdgcn_s_sleep(1);
      }
      // Full h row-panel for this wave: 32 k-steps x 16B/lane.
      const unsigned short* hrow = hcur + (size_t)(bb + r) * L_ + lk8;
      short8 hf[32];
      #pragma unroll
      for (int j = 0; j < 32; ++j)
        ld_x4(hf[j], hrow + j * 32);
      asm volatile("s_waitcnt vmcnt(0)" ::: "memory");
      __builtin_amdgcn_sched_barrier(0);
      #pragma unroll
      for (int j = 0; j < 32; ++j) {
        const unsigned k = (unsigned)(IN_ + j * 32 + lk8);
        short8 b = *(const short8*)(wbase + ((k * 2u) ^ swz));
        acc[j & 3] = __builtin_amdgcn_mfma_f32_16x16x32_bf16(
                       __builtin_bit_cast(bf16x8, hf[j]), __builtin_bit_cast(bf16x8, b),
                       acc[j & 3], 0, 0, 0);
      }
    }

    // ---- finalize: sum chains, tanh, publish 4 shorts, drain, raise flag ----
    #pragma unroll
    for (int j = 0; j < 4; ++j) {
      float s = (acc[0][j] + acc[1][j]) + (acc[2][j] + acc[3][j]);
      float hv = fast_tanh(s);
      // C/D layout (verified): col = lane&15, row = (lane>>4)*4 + reg
      st_us(hnxt + (size_t)(bb + (l >> 4) * 4 + j) * L_ + cc + r, f2b(hv));
    }
    asm volatile("s_waitcnt vmcnt(0)" ::: "memory");   // drains only our 4 stores
    if (l == 0)
      __hip_atomic_store(myflag, (unsigned)(t + 1), __ATOMIC_RELAXED, __HIP_MEMORY_SCOPE_AGENT);
  }
}

__global__ __launch_bounds__(256)
void decode_kernel(const unsigned short* __restrict__ hfin,
                   const float* __restrict__ Wdec, const float* __restrict__ bdec,
                   float* __restrict__ out)
{
  __shared__ float hrow[L_];
  const int b = blockIdx.x, tid = threadIdx.x;
  for (int k = tid; k < L_; k += 256)
    hrow[k] = b2f(hfin[b * L_ + k]);
  __syncthreads();
  float s = bdec[tid];
  const float* wr = Wdec + (size_t)tid * L_;
  #pragma unroll 4
  for (int k = 0; k < L_; k += 4) {
    f32x4 wq = *(const f32x4*)(wr + k);
    s += hrow[k] * wq[0] + hrow[k+1] * wq[1] + hrow[k+2] * wq[2] + hrow[k+3] * wq[3];
  }
  out[b * OUT_ + tid] = fast_tanh(s);
}

extern "C" void kernel_launch(void* const* d_in, const int* in_sizes, int n_in,
                              void* d_out, int out_size, void* d_ws, size_t ws_size,
                              hipStream_t stream)
{
  const float* x    = (const float*)d_in[0];
  const float* Wlin = (const float*)d_in[1];
  const float* Wdec = (const float*)d_in[2];
  const float* bdec = (const float*)d_in[3];
  float* out = (float*)d_out;

  // ws layout: h double buffer (2 x 128x1024 bf16 = 512 KB) + flags (32 KB).
  unsigned short* h0 = (unsigned short*)d_ws;
  unsigned short* h1 = h0 + (size_t)B_ * L_;
  unsigned int* flags = (unsigned int*)((char*)d_ws + (size_t)2 * B_ * L_ * 2);

  hipMemsetAsync(flags, 0, (size_t)GROUPS * NWAVE * 16 * sizeof(unsigned int), stream);

  hipFuncSetAttribute((const void*)rnn_persistent,
                      hipFuncAttributeMaxDynamicSharedMemorySize, LDS_TOTAL);

  hipLaunchKernelGGL(rnn_persistent, dim3(GROUPS * 32), dim3(128), LDS_TOTAL, stream,
                     x, Wlin, h0, h1, flags);
  // final h = h_1024, parity (1024 & 1) = 0 -> h0
  hipLaunchKernelGGL(decode_kernel, dim3(B_), dim3(256), 0, stream,
                     h0, Wdec, bdec, out);
}

// Round 9
// 3242.832 us; speedup vs baseline: 1.4049x; 1.4049x over previous
//
#include <hip/hip_runtime.h>
#include <hip/hip_bf16.h>
#include <stdint.h>

// Problem constants
#define B_    128
#define T_    1024
#define IN_   256
#define L_    1024
#define OUT_  256
#define KTOT  1280   // IN_ + L_

// Decomposition: 8 groups x 16 batches; each group = 32 WGs x 32 latent cols.
// Sync: clock-paced lockstep (s_memrealtime, 100 MHz chip-global) + sentinel
// ring validation. No flags, no drains, no polling on the critical path.
#define GROUPS 8
#define WPG    32
#define NB     16
#define NC     32
#define PAD_K  1288                       // 1280 + 8 bf16 pad
#define LDS_W_BYTES (NC * PAD_K * 2)      // 82432
#define RED_BYTES   (8 * 4 * 64 * 4)      // 8192
#define STILE_BYTES (16 * 32 * 2)         // 1024
#define LDS_TOTAL   (LDS_W_BYTES + RED_BYTES + STILE_BYTES)   // 91648

#define SENT      0x7F807F80u             // two bf16 +inf: tanh can never produce
#define SLOT      (B_ * L_)               // elements per ring slot (bf16)
#define RETRY_CAP 200000                  // terminating safety valve
#define C_TICKS   80ull                   // 0.8 us pace gap (10 ns realtime ticks)

using short8 = __attribute__((ext_vector_type(8))) short;
using bf16x8 = __attribute__((ext_vector_type(8))) __bf16;
using f32x4  = __attribute__((ext_vector_type(4))) float;
using u32x4  = __attribute__((ext_vector_type(4))) unsigned;

__device__ __forceinline__ unsigned short f2b(float f) {   // fp32 -> bf16 RNE
  unsigned u = __builtin_bit_cast(unsigned, f);
  u += 0x7FFFu + ((u >> 16) & 1u);
  return (unsigned short)(u >> 16);
}
__device__ __forceinline__ float b2f(unsigned short h) {
  unsigned u = ((unsigned)h) << 16;
  return __builtin_bit_cast(float, u);
}
__device__ __forceinline__ float fast_tanh(float z) {
  z = fminf(fmaxf(z, -30.f), 30.f);
  float e2 = __expf(2.f * z);
  return __fdividef(e2 - 1.f, e2 + 1.f);
}
__device__ __forceinline__ int chunk_ok(short8 c) {
  u32x4 u = __builtin_bit_cast(u32x4, c);
  return (u[0] != SENT) & (u[1] != SENT) & (u[2] != SENT) & (u[3] != SENT);
}
// Device-scope (sc1) data movement — coherent across XCDs at the MALL
// (R7 verified sc1 == sc0 sc1 in both correctness and latency).
__device__ __forceinline__ void st_dw(unsigned int* p, unsigned int v) {
  asm volatile("global_store_dword %0, %1, off sc1" :: "v"(p), "v"(v) : "memory");
}
__device__ __forceinline__ void ld_x4(short8& d, const unsigned short* p) {
  asm volatile("global_load_dwordx4 %0, %1, off sc1 nt" : "=v"(d) : "v"(p) : "memory");
}

__global__ void init_ws(unsigned int* ring_dw) {
  size_t i = (size_t)blockIdx.x * 256 + threadIdx.x;
  const size_t total = (size_t)4 * SLOT / 2;   // dwords in 4 slots
  for (size_t k = i; k < total; k += (size_t)256 * 256) ring_dw[k] = SENT;
}

__global__ __launch_bounds__(256, 1)
void rnn_persistent(const float* __restrict__ x, const float* __restrict__ Wlin,
                    unsigned short* __restrict__ ring)
{
  extern __shared__ char smem[];
  short* Wlds = (short*)smem;                                   // [NC][PAD_K] bf16
  float* red  = (float*)(smem + LDS_W_BYTES);
  unsigned short* stile = (unsigned short*)(smem + LDS_W_BYTES + RED_BYTES); // [16][32]

  const int tid = threadIdx.x;
  const int g   = blockIdx.x & 7;       // group (XCD locality heuristic only)
  const int w   = blockIdx.x >> 3;      // 0..31: col slice
  const int bb  = g * NB;
  const int cc  = w * NC;

  // ---- one-time: stage this WG's weight rows (bf16) into LDS ----
  for (int r = 0; r < NC; ++r) {
    const float* wrow = Wlin + (size_t)(cc + r) * KTOT;
    for (int k = tid; k < KTOT; k += 256)
      Wlds[r * PAD_K + k] = (short)f2b(wrow[k]);
  }
  __syncthreads();

  const int wv   = tid >> 6;            // wave 0..3 (K-split)
  const int l    = tid & 63;
  const int lrow = l & 15;              // M-row (A) / N-col (B) within tile
  const int lk   = (l >> 4) * 8;        // K offset within k-step
  const int prow = tid >> 4;            // publish/reset row 0..15
  const int pcol = tid & 15;            // publish/reset dword col 0..15

  uint64_t dl = 0;                      // probe deadline (realtime ticks)

  for (int t = 0; t < T_; ++t) {
    const unsigned short* hcur = ring + (size_t)(t & 3) * SLOT;       // h_t
    unsigned short*       hnxt = ring + (size_t)((t + 1) & 3) * SLOT; // h_{t+1}

    // ---- 1. fire-and-forget re-sentinel of slot (t+2)&3 (holds dead h_{t-2}).
    // Race-free: h_{t-1} validated at step t-1 => all peers finished step t-2
    // publishes => all their h_{t-2} reads drained. Our reset is ordered before
    // our own h_{t+2} publish by step t+1's h-load vmcnt(0). ----
    if (t >= 2) {
      unsigned int* rp = (unsigned int*)(ring + (size_t)((t + 2) & 3) * SLOT
                                         + (size_t)(bb + prow) * L_ + cc) + pcol;
      st_dw(rp, SENT);
    }

    f32x4 acc0 = {0.f, 0.f, 0.f, 0.f};
    f32x4 acc1 = {0.f, 0.f, 0.f, 0.f};

    // ---- 2. x part (K 0..255): cached loads, entirely off the paced path ----
    #pragma unroll
    for (int j = 0; j < 2; ++j) {
      const int kk    = wv + 4 * j;
      const int kbase = kk * 32 + lk;
      const float* xp = x + ((size_t)(bb + lrow) * T_ + t) * IN_ + kbase;
      f32x4 x0 = *(const f32x4*)xp;
      f32x4 x1 = *(const f32x4*)(xp + 4);
      short8 a;
      a[0] = (short)f2b(x0[0]); a[1] = (short)f2b(x0[1]);
      a[2] = (short)f2b(x0[2]); a[3] = (short)f2b(x0[3]);
      a[4] = (short)f2b(x1[0]); a[5] = (short)f2b(x1[1]);
      a[6] = (short)f2b(x1[2]); a[7] = (short)f2b(x1[3]);
      short8 b0 = *(const short8*)&Wlds[lrow        * PAD_K + kbase];
      short8 b1 = *(const short8*)&Wlds[(lrow + 16) * PAD_K + kbase];
      acc0 = __builtin_amdgcn_mfma_f32_16x16x32_bf16(
               __builtin_bit_cast(bf16x8, a), __builtin_bit_cast(bf16x8, b0), acc0, 0, 0, 0);
      acc1 = __builtin_amdgcn_mfma_f32_16x16x32_bf16(
               __builtin_bit_cast(bf16x8, a), __builtin_bit_cast(bf16x8, b1), acc1, 0, 0, 0);
    }

    // ---- 3. h part: spin to deadline (no memory traffic), then one-shot load
    //          + sentinel validate; chunk-granular bounded retry fallback ----
    if (t > 0) {
      while (__builtin_amdgcn_s_memrealtime() < dl)
        __builtin_amdgcn_s_sleep(1);

      const unsigned short* hbase = hcur + (size_t)(bb + lrow) * L_ + wv * 32 + lk;
      short8 hf[8];
      #pragma unroll
      for (int j = 0; j < 8; ++j)
        ld_x4(hf[j], hbase + j * 128);
      asm volatile("s_waitcnt vmcnt(0)" ::: "memory");   // also drains resets
      __builtin_amdgcn_sched_barrier(0);

      bool okj[8] = {false, false, false, false, false, false, false, false};
      int remaining = 8, tries = 0;
      while (true) {
        #pragma unroll
        for (int j = 0; j < 8; ++j)
          if (!okj[j] && __all(chunk_ok(hf[j]))) { okj[j] = true; --remaining; }
        if (remaining == 0) break;
        if (++tries > RETRY_CAP) break;                  // never hang
        __builtin_amdgcn_s_sleep(2);                     // ~128 cy backoff
        #pragma unroll
        for (int j = 0; j < 8; ++j)
          if (!okj[j]) ld_x4(hf[j], hbase + j * 128);
        asm volatile("s_waitcnt vmcnt(0)" ::: "memory");
        __builtin_amdgcn_sched_barrier(0);
      }
      // Self-correcting pace: next step's data will be ready ~C after now.
      dl = __builtin_amdgcn_s_memrealtime() + C_TICKS;

      #pragma unroll
      for (int j = 0; j < 8; ++j) {
        const int kbase = IN_ + wv * 32 + j * 128 + lk;
        short8 b0 = *(const short8*)&Wlds[lrow        * PAD_K + kbase];
        short8 b1 = *(const short8*)&Wlds[(lrow + 16) * PAD_K + kbase];
        acc0 = __builtin_amdgcn_mfma_f32_16x16x32_bf16(
                 __builtin_bit_cast(bf16x8, hf[j]), __builtin_bit_cast(bf16x8, b0), acc0, 0, 0, 0);
        acc1 = __builtin_amdgcn_mfma_f32_16x16x32_bf16(
                 __builtin_bit_cast(bf16x8, hf[j]), __builtin_bit_cast(bf16x8, b1), acc1, 0, 0, 0);
      }
    }

    // ---- 4. cross-wave K reduction via LDS, tanh, assemble tile ----
    #pragma unroll
    for (int j = 0; j < 4; ++j) {
      red[((wv * 2 + 0) * 4 + j) * 64 + l] = acc0[j];
      red[((wv * 2 + 1) * 4 + j) * 64 + l] = acc1[j];
    }
    __syncthreads();
    if (wv < 2) {
      const int tile = wv;
      #pragma unroll
      for (int j = 0; j < 4; ++j) {
        float s = red[((0 * 2 + tile) * 4 + j) * 64 + l]
                + red[((1 * 2 + tile) * 4 + j) * 64 + l]
                + red[((2 * 2 + tile) * 4 + j) * 64 + l]
                + red[((3 * 2 + tile) * 4 + j) * 64 + l];
        float hv = fast_tanh(s);
        // C/D layout: col = lane&15, row = (lane>>4)*4 + reg
        stile[((l >> 4) * 4 + j) * 32 + tile * 16 + (l & 15)] = f2b(hv);
      }
    }
    __syncthreads();

    // ---- 5. publish: fire-and-forget dword stores (data self-validates).
    // No drain, no flag. Next step's vmcnt(0) orders everything. ----
    {
      unsigned int v = ((const unsigned int*)stile)[tid];
      unsigned int* dp = (unsigned int*)(hnxt + (size_t)(bb + prow) * L_ + cc) + pcol;
      st_dw(dp, v);
    }
    if (t == 0)
      dl = __builtin_amdgcn_s_memrealtime() + C_TICKS;
  }
}

__global__ __launch_bounds__(256)
void decode_kernel(const unsigned short* __restrict__ hfin,
                   const float* __restrict__ Wdec, const float* __restrict__ bdec,
                   float* __restrict__ out)
{
  __shared__ float hrow[L_];
  const int b = blockIdx.x, tid = threadIdx.x;
  for (int k = tid; k < L_; k += 256)
    hrow[k] = b2f(hfin[b * L_ + k]);
  __syncthreads();
  float s = bdec[tid];
  const float* wr = Wdec + (size_t)tid * L_;
  #pragma unroll 4
  for (int k = 0; k < L_; k += 4) {
    f32x4 wq = *(const f32x4*)(wr + k);
    s += hrow[k] * wq[0] + hrow[k+1] * wq[1] + hrow[k+2] * wq[2] + hrow[k+3] * wq[3];
  }
  out[b * OUT_ + tid] = fast_tanh(s);
}

extern "C" void kernel_launch(void* const* d_in, const int* in_sizes, int n_in,
                              void* d_out, int out_size, void* d_ws, size_t ws_size,
                              hipStream_t stream)
{
  const float* x    = (const float*)d_in[0];
  const float* Wlin = (const float*)d_in[1];
  const float* Wdec = (const float*)d_in[2];
  const float* bdec = (const float*)d_in[3];
  float* out = (float*)d_out;

  // ws layout: 4-slot h ring (4 x 128x1024 bf16 = 1 MB).
  unsigned short* ring = (unsigned short*)d_ws;

  hipFuncSetAttribute((const void*)rnn_persistent,
                      hipFuncAttributeMaxDynamicSharedMemorySize, LDS_TOTAL);

  hipLaunchKernelGGL(init_ws, dim3(256), dim3(256), 0, stream,
                     (unsigned int*)ring);
  hipLaunchKernelGGL(rnn_persistent, dim3(GROUPS * WPG), dim3(256), LDS_TOTAL, stream,
                     x, Wlin, ring);
  // final h = h_1024, in slot (1024 & 3) = 0
  hipLaunchKernelGGL(decode_kernel, dim3(B_), dim3(256), 0, stream,
                     ring, Wdec, bdec, out);
}

// Round 10
// 3231.770 us; speedup vs baseline: 1.4097x; 1.0034x over previous
//
#include <hip/hip_runtime.h>
#include <hip/hip_bf16.h>
#include <stdint.h>

// Problem constants
#define B_    128
#define T_    1024
#define IN_   256
#define L_    1024
#define OUT_  256
#define KTOT  1280   // IN_ + L_

// Decomposition: 8 groups x 16 batches; each group = 32 WGs x 32 latent cols.
// Sync: sentinel-ring (race-free, R9-proven) + ADAPTIVE clock pacing.
// R9 lesson: s_memrealtime ticks at 25 MHz (40 ns), not 100 MHz — R9 was
// self-paced to 3.2 us/step. The controller below is tick-frequency-agnostic.
#define GROUPS 8
#define WPG    32
#define NB     16
#define NC     32
#define PAD_K  1288                       // 1280 + 8 bf16 pad
#define LDS_W_BYTES (NC * PAD_K * 2)      // 82432
#define RED_BYTES   (8 * 4 * 64 * 4)      // 8192
#define STILE_BYTES (16 * 32 * 2)         // 1024
#define LDS_TOTAL   (LDS_W_BYTES + RED_BYTES + STILE_BYTES)   // 91648

#define SENT      0x7F807F80u             // two bf16 +inf: tanh can never produce
#define SLOT      (B_ * L_)               // elements per ring slot (bf16)
#define RETRY_CAP 200000                  // terminating safety valve
#define GAP_MIN   4u
#define GAP_MAX   800u
#define GAP_INIT  16u

using short8 = __attribute__((ext_vector_type(8))) short;
using bf16x8 = __attribute__((ext_vector_type(8))) __bf16;
using f32x4  = __attribute__((ext_vector_type(4))) float;
using u32x4  = __attribute__((ext_vector_type(4))) unsigned;

__device__ __forceinline__ unsigned short f2b(float f) {   // fp32 -> bf16 RNE
  unsigned u = __builtin_bit_cast(unsigned, f);
  u += 0x7FFFu + ((u >> 16) & 1u);
  return (unsigned short)(u >> 16);
}
__device__ __forceinline__ float b2f(unsigned short h) {
  unsigned u = ((unsigned)h) << 16;
  return __builtin_bit_cast(float, u);
}
__device__ __forceinline__ float fast_tanh(float z) {
  z = fminf(fmaxf(z, -30.f), 30.f);
  float e2 = __expf(2.f * z);
  return __fdividef(e2 - 1.f, e2 + 1.f);
}
__device__ __forceinline__ int chunk_ok(short8 c) {
  u32x4 u = __builtin_bit_cast(u32x4, c);
  return (u[0] != SENT) & (u[1] != SENT) & (u[2] != SENT) & (u[3] != SENT);
}
// Device-scope (sc1) — coherent across XCDs at the MALL (R7: == sc0 sc1).
__device__ __forceinline__ void st_dw(unsigned int* p, unsigned int v) {
  asm volatile("global_store_dword %0, %1, off sc1" :: "v"(p), "v"(v) : "memory");
}
__device__ __forceinline__ void ld_x4(short8& d, const unsigned short* p) {
  asm volatile("global_load_dwordx4 %0, %1, off sc1 nt" : "=v"(d) : "v"(p) : "memory");
}

__global__ void init_ws(unsigned int* ring_dw) {
  size_t i = (size_t)blockIdx.x * 256 + threadIdx.x;
  const size_t total = (size_t)4 * SLOT / 2;   // dwords in 4 slots
  for (size_t k = i; k < total; k += (size_t)256 * 256) ring_dw[k] = SENT;
}

__global__ __launch_bounds__(256, 1)
void rnn_persistent(const float* __restrict__ x, const float* __restrict__ Wlin,
                    unsigned short* __restrict__ ring)
{
  extern __shared__ char smem[];
  short* Wlds = (short*)smem;                                   // [NC][PAD_K] bf16
  float* red  = (float*)(smem + LDS_W_BYTES);
  unsigned short* stile = (unsigned short*)(smem + LDS_W_BYTES + RED_BYTES); // [16][32]

  const int tid = threadIdx.x;
  const int g   = blockIdx.x & 7;       // group (XCD locality heuristic only)
  const int w   = blockIdx.x >> 3;      // 0..31: col slice
  const int bb  = g * NB;
  const int cc  = w * NC;

  // ---- one-time: stage this WG's weight rows (bf16) into LDS ----
  for (int r = 0; r < NC; ++r) {
    const float* wrow = Wlin + (size_t)(cc + r) * KTOT;
    for (int k = tid; k < KTOT; k += 256)
      Wlds[r * PAD_K + k] = (short)f2b(wrow[k]);
  }
  __syncthreads();

  const int wv   = tid >> 6;            // wave 0..3 (K-split)
  const int l    = tid & 63;
  const int lrow = l & 15;              // M-row (A) / N-col (B) within tile
  const int lk   = (l >> 4) * 8;        // K offset within k-step
  const int prow = tid >> 4;            // publish/reset row 0..15
  const int pcol = tid & 15;            // publish/reset dword col 0..15

  uint64_t pub_ts = 0;                  // realtime at our last publish-issue
  unsigned gap    = GAP_INIT;           // adaptive probe gap (ticks)

  for (int t = 0; t < T_; ++t) {
    const unsigned short* hcur = ring + (size_t)(t & 3) * SLOT;       // h_t
    unsigned short*       hnxt = ring + (size_t)((t + 1) & 3) * SLOT; // h_{t+1}

    // ---- 1. fire-and-forget re-sentinel of slot (t+2)&3 (dead h_{t-2}).
    // Race-free by validation causality (see R9); ordered before our own
    // h_{t+2} publish by the next step's h-load vmcnt(0). ----
    if (t >= 2) {
      unsigned int* rp = (unsigned int*)(ring + (size_t)((t + 2) & 3) * SLOT
                                         + (size_t)(bb + prow) * L_ + cc) + pcol;
      st_dw(rp, SENT);
    }

    f32x4 acc0 = {0.f, 0.f, 0.f, 0.f};
    f32x4 acc1 = {0.f, 0.f, 0.f, 0.f};

    // ---- 2. x part (K 0..255): cached loads, hidden inside the gap wait ----
    #pragma unroll
    for (int j = 0; j < 2; ++j) {
      const int kk    = wv + 4 * j;
      const int kbase = kk * 32 + lk;
      const float* xp = x + ((size_t)(bb + lrow) * T_ + t) * IN_ + kbase;
      f32x4 x0 = *(const f32x4*)xp;
      f32x4 x1 = *(const f32x4*)(xp + 4);
      short8 a;
      a[0] = (short)f2b(x0[0]); a[1] = (short)f2b(x0[1]);
      a[2] = (short)f2b(x0[2]); a[3] = (short)f2b(x0[3]);
      a[4] = (short)f2b(x1[0]); a[5] = (short)f2b(x1[1]);
      a[6] = (short)f2b(x1[2]); a[7] = (short)f2b(x1[3]);
      short8 b0 = *(const short8*)&Wlds[lrow        * PAD_K + kbase];
      short8 b1 = *(const short8*)&Wlds[(lrow + 16) * PAD_K + kbase];
      acc0 = __builtin_amdgcn_mfma_f32_16x16x32_bf16(
               __builtin_bit_cast(bf16x8, a), __builtin_bit_cast(bf16x8, b0), acc0, 0, 0, 0);
      acc1 = __builtin_amdgcn_mfma_f32_16x16x32_bf16(
               __builtin_bit_cast(bf16x8, a), __builtin_bit_cast(bf16x8, b1), acc1, 0, 0, 0);
    }

    // ---- 3. h part: spin to (pub_ts + gap), one-shot load + validate;
    //          chunk-granular bounded retry; adaptive gap update ----
    if (t > 0) {
      const uint64_t dl = pub_ts + gap;
      while (__builtin_amdgcn_s_memrealtime() < dl)
        __builtin_amdgcn_s_sleep(1);

      const unsigned short* hbase = hcur + (size_t)(bb + lrow) * L_ + wv * 32 + lk;
      short8 hf[8];
      #pragma unroll
      for (int j = 0; j < 8; ++j)
        ld_x4(hf[j], hbase + j * 128);
      asm volatile("s_waitcnt vmcnt(0)" ::: "memory");   // also drains resets
      __builtin_amdgcn_sched_barrier(0);

      bool okj[8] = {false, false, false, false, false, false, false, false};
      int remaining = 8, tries = 0;
      while (true) {
        #pragma unroll
        for (int j = 0; j < 8; ++j)
          if (!okj[j] && __all(chunk_ok(hf[j]))) { okj[j] = true; --remaining; }
        if (remaining == 0) break;
        if (++tries > RETRY_CAP) break;                  // never hang
        __builtin_amdgcn_s_sleep(1);
        #pragma unroll
        for (int j = 0; j < 8; ++j)
          if (!okj[j]) ld_x4(hf[j], hbase + j * 128);
        asm volatile("s_waitcnt vmcnt(0)" ::: "memory");
        __builtin_amdgcn_sched_barrier(0);
      }
      // Controller: clean step -> tighten; retries -> widen proportionally.
      if (tries == 0)      gap = (gap > GAP_MIN) ? gap - 1 : gap;
      else { unsigned inc = (unsigned)tries << 3;
             gap = (gap + inc > GAP_MAX) ? GAP_MAX : gap + inc; }

      #pragma unroll
      for (int j = 0; j < 8; ++j) {
        const int kbase = IN_ + wv * 32 + j * 128 + lk;
        short8 b0 = *(const short8*)&Wlds[lrow        * PAD_K + kbase];
        short8 b1 = *(const short8*)&Wlds[(lrow + 16) * PAD_K + kbase];
        acc0 = __builtin_amdgcn_mfma_f32_16x16x32_bf16(
                 __builtin_bit_cast(bf16x8, hf[j]), __builtin_bit_cast(bf16x8, b0), acc0, 0, 0, 0);
        acc1 = __builtin_amdgcn_mfma_f32_16x16x32_bf16(
                 __builtin_bit_cast(bf16x8, hf[j]), __builtin_bit_cast(bf16x8, b1), acc1, 0, 0, 0);
      }
    }

    // ---- 4. cross-wave K reduction via LDS, tanh, assemble tile ----
    #pragma unroll
    for (int j = 0; j < 4; ++j) {
      red[((wv * 2 + 0) * 4 + j) * 64 + l] = acc0[j];
      red[((wv * 2 + 1) * 4 + j) * 64 + l] = acc1[j];
    }
    __syncthreads();
    if (wv < 2) {
      const int tile = wv;
      #pragma unroll
      for (int j = 0; j < 4; ++j) {
        float s = red[((0 * 2 + tile) * 4 + j) * 64 + l]
                + red[((1 * 2 + tile) * 4 + j) * 64 + l]
                + red[((2 * 2 + tile) * 4 + j) * 64 + l]
                + red[((3 * 2 + tile) * 4 + j) * 64 + l];
        float hv = fast_tanh(s);
        // C/D layout: col = lane&15, row = (lane>>4)*4 + reg
        stile[((l >> 4) * 4 + j) * 32 + tile * 16 + (l & 15)] = f2b(hv);
      }
    }
    __syncthreads();

    // ---- 5. publish: fire-and-forget dword stores (data self-validates);
    //          record publish-issue time as next step's pace anchor ----
    {
      unsigned int v = ((const unsigned int*)stile)[tid];
      unsigned int* dp = (unsigned int*)(hnxt + (size_t)(bb + prow) * L_ + cc) + pcol;
      st_dw(dp, v);
    }
    pub_ts = __builtin_amdgcn_s_memrealtime();
  }
}

__global__ __launch_bounds__(256)
void decode_kernel(const unsigned short* __restrict__ hfin,
                   const float* __restrict__ Wdec, const float* __restrict__ bdec,
                   float* __restrict__ out)
{
  __shared__ float hrow[L_];
  const int b = blockIdx.x, tid = threadIdx.x;
  for (int k = tid; k < L_; k += 256)
    hrow[k] = b2f(hfin[b * L_ + k]);
  __syncthreads();
  float s = bdec[tid];
  const float* wr = Wdec + (size_t)tid * L_;
  #pragma unroll 4
  for (int k = 0; k < L_; k += 4) {
    f32x4 wq = *(const f32x4*)(wr + k);
    s += hrow[k] * wq[0] + hrow[k+1] * wq[1] + hrow[k+2] * wq[2] + hrow[k+3] * wq[3];
  }
  out[b * OUT_ + tid] = fast_tanh(s);
}

extern "C" void kernel_launch(void* const* d_in, const int* in_sizes, int n_in,
                              void* d_out, int out_size, void* d_ws, size_t ws_size,
                              hipStream_t stream)
{
  const float* x    = (const float*)d_in[0];
  const float* Wlin = (const float*)d_in[1];
  const float* Wdec = (const float*)d_in[2];
  const float* bdec = (const float*)d_in[3];
  float* out = (float*)d_out;

  // ws layout: 4-slot h ring (4 x 128x1024 bf16 = 1 MB).
  unsigned short* ring = (unsigned short*)d_ws;

  hipFuncSetAttribute((const void*)rnn_persistent,
                      hipFuncAttributeMaxDynamicSharedMemorySize, LDS_TOTAL);

  hipLaunchKernelGGL(init_ws, dim3(256), dim3(256), 0, stream,
                     (unsigned int*)ring);
  hipLaunchKernelGGL(rnn_persistent, dim3(GROUPS * WPG), dim3(256), LDS_TOTAL, stream,
                     x, Wlin, ring);
  // final h = h_1024, in slot (1024 & 3) = 0
  hipLaunchKernelGGL(decode_kernel, dim3(B_), dim3(256), 0, stream,
                     ring, Wdec, bdec, out);
}